// Round 1
// baseline (226.028 us; speedup 1.0000x reference)
//
#include <hip/hip_runtime.h>
#include <hip/hip_bf16.h>
#include <stdint.h>

typedef __attribute__((ext_vector_type(4))) short short4v;
typedef __attribute__((ext_vector_type(8))) short short8v;
typedef __attribute__((ext_vector_type(4))) float f32x4;

__device__ __forceinline__ unsigned short f2bf(float f) {
  unsigned int u = __float_as_uint(f);
  u += 0x7fffu + ((u >> 16) & 1u);
  return (unsigned short)(u >> 16);
}

// ---- CSR build ----
__global__ void k_init(int* deg, int* cursor, int N) {
  int i = blockIdx.x * blockDim.x + threadIdx.x;
  if (i < N) { deg[i] = 1; cursor[i] = 0; }   // deg starts at 1 (self-loop)
}

__global__ void k_count(const int* __restrict__ dst, int* deg, int E) {
  int e = blockIdx.x * blockDim.x + threadIdx.x;
  if (e < E) atomicAdd(&deg[dst[e]], 1);
}

__global__ void k_dis(const int* __restrict__ deg, float* dis, int N) {
  int i = blockIdx.x * blockDim.x + threadIdx.x;
  if (i < N) dis[i] = rsqrtf((float)deg[i]);
}

__global__ void k_blocksum(const int* __restrict__ deg, int* partials, int N) {
  __shared__ int s[256];
  int t = threadIdx.x;
  int i = blockIdx.x * 256 + t;
  s[t] = (i < N) ? (deg[i] - 1) : 0;
  __syncthreads();
  for (int off = 128; off > 0; off >>= 1) {
    if (t < off) s[t] += s[t + off];
    __syncthreads();
  }
  if (t == 0) partials[blockIdx.x] = s[0];
}

__global__ void k_scan_partials(int* partials, int nb) {
  __shared__ int s[1024];
  int t = threadIdx.x;
  s[t] = (t < nb) ? partials[t] : 0;
  __syncthreads();
  for (int off = 1; off < 1024; off <<= 1) {
    int v = (t >= off) ? s[t - off] : 0;
    __syncthreads();
    s[t] += v;
    __syncthreads();
  }
  if (t < nb) partials[t] = (t == 0) ? 0 : s[t - 1];  // exclusive
}

__global__ void k_scan_final(const int* __restrict__ deg, const int* __restrict__ partials,
                             int* csr_off, int N, int E) {
  __shared__ int s[256];
  int t = threadIdx.x;
  int i = blockIdx.x * 256 + t;
  int c = (i < N) ? (deg[i] - 1) : 0;
  s[t] = c;
  __syncthreads();
  for (int off = 1; off < 256; off <<= 1) {
    int v = (t >= off) ? s[t - off] : 0;
    __syncthreads();
    s[t] += v;
    __syncthreads();
  }
  if (i < N) csr_off[i] = partials[blockIdx.x] + s[t] - c;  // exclusive
  if (i == 0) csr_off[N] = E;
}

__global__ void k_fill(const int* __restrict__ src, const int* __restrict__ dst,
                       const int* __restrict__ csr_off, int* cursor, int* csr_src, int E) {
  int e = blockIdx.x * blockDim.x + threadIdx.x;
  if (e < E) {
    int d = dst[e];
    int p = atomicAdd(&cursor[d], 1);
    csr_src[csr_off[d] + p] = src[e];
  }
}

// ---- pull-based aggregation: out[i] = dis[i]*(dis[i]*X[i] + sum dis[s]*X[s]) ----
__global__ __launch_bounds__(256) void k_agg(const float* __restrict__ X,
     const int* __restrict__ csr_src, const int* __restrict__ csr_off,
     const float* __restrict__ dis, float* __restrict__ out, int N) {
  int lane = threadIdx.x & 63;
  int gwave = (blockIdx.x * blockDim.x + threadIdx.x) >> 6;
  int nwave = (gridDim.x * blockDim.x) >> 6;
  for (int i = gwave; i < N; i += nwave) {
    float di = dis[i];
    float2 a = ((const float2*)(X + (size_t)i * 128))[lane];
    a.x *= di; a.y *= di;
    int e0 = csr_off[i], e1 = csr_off[i + 1];
    for (int e = e0; e < e1; ++e) {
      int sidx = csr_src[e];
      float dsv = dis[sidx];
      float2 v = ((const float2*)(X + (size_t)sidx * 128))[lane];
      a.x = fmaf(dsv, v.x, a.x);
      a.y = fmaf(dsv, v.y, a.y);
    }
    a.x *= di; a.y *= di;
    ((float2*)(out + (size_t)i * 128))[lane] = a;
  }
}

// ---- in-place GEMM: out[r,:] = bf16(out[r,:]) @ bf16(W) + b, 64 rows/block ----
__global__ __launch_bounds__(256) void k_gemm(const float* __restrict__ W,
     const float* __restrict__ bias, float* __restrict__ out, int N) {
  __shared__ unsigned short Wt[128 * 136];   // Wt[j*136+k] = bf16(W[k,j]) transposed, padded
  __shared__ unsigned short A[64 * 136];     // A[row*136+k]
  int t = threadIdx.x;
  for (int idx = t; idx < 128 * 128; idx += 256) {
    int k = idx >> 7, j = idx & 127;
    Wt[j * 136 + k] = f2bf(W[idx]);
  }
  int r0 = blockIdx.x * 64;
  const float4* srcp = (const float4*)(out + (size_t)r0 * 128);
  for (int q = t; q < 64 * 32; q += 256) {
    int row = q >> 5, c4 = q & 31;
    float4 v;
    if (r0 + row < N) v = srcp[row * 32 + c4];
    else { v.x = v.y = v.z = v.w = 0.f; }
    int base = row * 136 + c4 * 4;
    A[base + 0] = f2bf(v.x); A[base + 1] = f2bf(v.y);
    A[base + 2] = f2bf(v.z); A[base + 3] = f2bf(v.w);
  }
  __syncthreads();
  int wv = t >> 6, lane = t & 63;
  int lr = lane & 15, lg = lane >> 4;
  int arow = wv * 16 + lr;
  short8v afr[4];
  #pragma unroll
  for (int kt = 0; kt < 4; ++kt) {
    const unsigned short* ap = &A[arow * 136 + kt * 32 + 4 * lg];
    short4v lo = *(const short4v*)ap;
    short4v hi = *(const short4v*)(ap + 16);
    afr[kt] = __builtin_shufflevector(lo, hi, 0, 1, 2, 3, 4, 5, 6, 7);
  }
  #pragma unroll
  for (int ct = 0; ct < 8; ++ct) {
    f32x4 acc = {0.f, 0.f, 0.f, 0.f};
    #pragma unroll
    for (int kt = 0; kt < 4; ++kt) {
      const unsigned short* bp = &Wt[(ct * 16 + lr) * 136 + kt * 32 + 4 * lg];
      short4v lo = *(const short4v*)bp;
      short4v hi = *(const short4v*)(bp + 16);
      short8v bfr = __builtin_shufflevector(lo, hi, 0, 1, 2, 3, 4, 5, 6, 7);
      acc = __builtin_amdgcn_mfma_f32_16x16x32_bf16(afr[kt], bfr, acc, 0, 0, 0);
    }
    int col = ct * 16 + lr;
    float bb = bias[col];
    #pragma unroll
    for (int r = 0; r < 4; ++r) {
      int row = r0 + wv * 16 + lg * 4 + r;
      if (row < N) out[(size_t)row * 128 + col] = acc[r] + bb;
    }
  }
}

extern "C" void kernel_launch(void* const* d_in, const int* in_sizes, int n_in,
                              void* d_out, int out_size, void* d_ws, size_t ws_size,
                              hipStream_t stream) {
  const float* X    = (const float*)d_in[0];
  const int*   edge = (const int*)d_in[1];
  const float* W    = (const float*)d_in[2];
  const float* bias = (const float*)d_in[3];
  float* out = (float*)d_out;
  int N = in_sizes[0] / 128;
  int E = in_sizes[1] / 2;
  const int* srcArr = edge;
  const int* dstArr = edge + E;

  char* w = (char*)d_ws;
  auto align = [](size_t x) { return (x + 255) & ~(size_t)255; };
  size_t o = 0;
  int*   deg      = (int*)(w + o);   o += align((size_t)N * 4);
  float* dis      = (float*)(w + o); o += align((size_t)N * 4);
  int*   cursor   = (int*)(w + o);   o += align((size_t)N * 4);
  int*   csr_off  = (int*)(w + o);   o += align(((size_t)N + 1) * 4);
  int*   csr_src  = (int*)(w + o);   o += align((size_t)E * 4);
  int*   partials = (int*)(w + o);

  int nbN = (N + 255) / 256;
  int nbE = (E + 255) / 256;

  k_init<<<nbN, 256, 0, stream>>>(deg, cursor, N);
  k_count<<<nbE, 256, 0, stream>>>(dstArr, deg, E);
  k_dis<<<nbN, 256, 0, stream>>>(deg, dis, N);
  k_blocksum<<<nbN, 256, 0, stream>>>(deg, partials, N);
  k_scan_partials<<<1, 1024, 0, stream>>>(partials, nbN);
  k_scan_final<<<nbN, 256, 0, stream>>>(deg, partials, csr_off, N, E);
  k_fill<<<nbE, 256, 0, stream>>>(srcArr, dstArr, csr_off, cursor, csr_src, E);
  k_agg<<<2048, 256, 0, stream>>>(X, csr_src, csr_off, dis, out, N);
  k_gemm<<<(N + 63) / 64, 256, 0, stream>>>(W, bias, out, N);
}

// Round 2
// 199.909 us; speedup vs baseline: 1.1307x; 1.1307x over previous
//
#include <hip/hip_runtime.h>
#include <hip/hip_bf16.h>
#include <stdint.h>

typedef __attribute__((ext_vector_type(4))) short short4v;
typedef __attribute__((ext_vector_type(8))) short short8v;
typedef __attribute__((ext_vector_type(4))) float f32x4;

__device__ __forceinline__ unsigned short f2bf(float f) {
  unsigned int u = __float_as_uint(f);
  u += 0x7fffu + ((u >> 16) & 1u);
  return (unsigned short)(u >> 16);
}
__device__ __forceinline__ float bf_lo(unsigned int v) { return __uint_as_float(v << 16); }
__device__ __forceinline__ float bf_hi(unsigned int v) { return __uint_as_float(v & 0xffff0000u); }

// ---- CSR build ----
__global__ void k_init(int* deg, int* cursor, int N) {
  int i = blockIdx.x * blockDim.x + threadIdx.x;
  if (i < N) { deg[i] = 0; cursor[i] = 0; }   // deg = in-edge count (self-loop excluded)
}

__global__ void k_count(const int* __restrict__ dst, int* deg, int E) {
  int e = blockIdx.x * blockDim.x + threadIdx.x;
  if (e < E) atomicAdd(&deg[dst[e]], 1);
}

// block-sums of deg for the scan, plus dis = rsqrt(deg+1)
__global__ void k_blocksum(const int* __restrict__ deg, int* partials, float* dis, int N) {
  __shared__ int s[256];
  int t = threadIdx.x;
  int i = blockIdx.x * 256 + t;
  int c = (i < N) ? deg[i] : 0;
  if (i < N) dis[i] = rsqrtf((float)(c + 1));
  s[t] = c;
  __syncthreads();
  for (int off = 128; off > 0; off >>= 1) {
    if (t < off) s[t] += s[t + off];
    __syncthreads();
  }
  if (t == 0) partials[blockIdx.x] = s[0];
}

__global__ void k_scan_partials(int* partials, int nb) {
  __shared__ int s[1024];
  int t = threadIdx.x;
  s[t] = (t < nb) ? partials[t] : 0;
  __syncthreads();
  for (int off = 1; off < 1024; off <<= 1) {
    int v = (t >= off) ? s[t - off] : 0;
    __syncthreads();
    s[t] += v;
    __syncthreads();
  }
  if (t < nb) partials[t] = (t == 0) ? 0 : s[t - 1];  // exclusive
}

__global__ void k_scan_final(const int* __restrict__ deg, const int* __restrict__ partials,
                             int* csr_off, int N, int E) {
  __shared__ int s[256];
  int t = threadIdx.x;
  int i = blockIdx.x * 256 + t;
  int c = (i < N) ? deg[i] : 0;
  s[t] = c;
  __syncthreads();
  for (int off = 1; off < 256; off <<= 1) {
    int v = (t >= off) ? s[t - off] : 0;
    __syncthreads();
    s[t] += v;
    __syncthreads();
  }
  if (i < N) csr_off[i] = partials[blockIdx.x] + s[t] - c;  // exclusive
  if (i == 0) csr_off[N] = E;
}

__global__ void k_fill(const int* __restrict__ src, const int* __restrict__ dst,
                       const int* __restrict__ csr_off, int* cursor, int* csr_src, int E) {
  int e = blockIdx.x * blockDim.x + threadIdx.x;
  if (e < E) {
    int d = dst[e];
    int p = atomicAdd(&cursor[d], 1);
    csr_src[csr_off[d] + p] = src[e];
  }
}

// ---- plan B: GEMM first -> hs = bf16(dis[i] * (X @ W)) ----
__global__ __launch_bounds__(256) void k_gemm_hs(const float* __restrict__ X,
     const float* __restrict__ W, const float* __restrict__ dis,
     unsigned short* __restrict__ hs, int N) {
  __shared__ unsigned short Wt[128 * 136];   // Wt[j*136+k] = bf16(W[k,j])
  __shared__ unsigned short A[64 * 136];
  int t = threadIdx.x;
  for (int idx = t; idx < 128 * 128; idx += 256) {
    int k = idx >> 7, j = idx & 127;
    Wt[j * 136 + k] = f2bf(W[idx]);
  }
  int r0 = blockIdx.x * 64;
  const float4* srcp = (const float4*)(X + (size_t)r0 * 128);
  for (int q = t; q < 64 * 32; q += 256) {
    int row = q >> 5, c4 = q & 31;
    float4 v;
    if (r0 + row < N) v = srcp[row * 32 + c4];
    else { v.x = v.y = v.z = v.w = 0.f; }
    int base = row * 136 + c4 * 4;
    A[base + 0] = f2bf(v.x); A[base + 1] = f2bf(v.y);
    A[base + 2] = f2bf(v.z); A[base + 3] = f2bf(v.w);
  }
  __syncthreads();
  int wv = t >> 6, lane = t & 63;
  int lr = lane & 15, lg = lane >> 4;
  int arow = wv * 16 + lr;
  short8v afr[4];
  #pragma unroll
  for (int kt = 0; kt < 4; ++kt) {
    const unsigned short* ap = &A[arow * 136 + kt * 32 + 4 * lg];
    short4v lo = *(const short4v*)ap;
    short4v hi = *(const short4v*)(ap + 16);
    afr[kt] = __builtin_shufflevector(lo, hi, 0, 1, 2, 3, 4, 5, 6, 7);
  }
  float dmul[4];
  #pragma unroll
  for (int r = 0; r < 4; ++r) {
    int gr = r0 + wv * 16 + lg * 4 + r;
    dmul[r] = (gr < N) ? dis[gr] : 0.f;
  }
  #pragma unroll
  for (int ct = 0; ct < 8; ++ct) {
    f32x4 acc = {0.f, 0.f, 0.f, 0.f};
    #pragma unroll
    for (int kt = 0; kt < 4; ++kt) {
      const unsigned short* bp = &Wt[(ct * 16 + lr) * 136 + kt * 32 + 4 * lg];
      short4v lo = *(const short4v*)bp;
      short4v hi = *(const short4v*)(bp + 16);
      short8v bfr = __builtin_shufflevector(lo, hi, 0, 1, 2, 3, 4, 5, 6, 7);
      acc = __builtin_amdgcn_mfma_f32_16x16x32_bf16(afr[kt], bfr, acc, 0, 0, 0);
    }
    int col = ct * 16 + lr;
    #pragma unroll
    for (int r = 0; r < 4; ++r) {
      int row = r0 + wv * 16 + lg * 4 + r;
      if (row < N) hs[(size_t)row * 128 + col] = f2bf(acc[r] * dmul[r]);
    }
  }
}

// ---- plan B: pull-aggregate bf16 hs: out[i] = dis[i]*(hs[i] + sum hs[s]) + b ----
__global__ __launch_bounds__(256) void k_agg_bf(const unsigned short* __restrict__ hs,
     const int* __restrict__ csr_src, const int* __restrict__ csr_off,
     const float* __restrict__ dis, const float* __restrict__ bias,
     float* __restrict__ out, int N) {
  int lane = threadIdx.x & 63;
  int gw = (blockIdx.x * blockDim.x + threadIdx.x) >> 6;
  int nw = (gridDim.x * blockDim.x) >> 6;
  int npw = (N + nw - 1) / nw;
  int i0 = gw * npw;
  int i1 = (i0 + npw < N) ? (i0 + npw) : N;
  if (i0 >= N) return;
  float2 bb = ((const float2*)bias)[lane];
  int e1prev = csr_off[i0];
  for (int i = i0; i < i1; ++i) {
    int e0 = e1prev;
    int e1 = csr_off[i + 1];
    e1prev = e1;
    unsigned int v = ((const unsigned int*)(hs + (size_t)i * 128))[lane];
    float ax = bf_lo(v), ay = bf_hi(v);
    int e = e0;
    for (; e + 1 < e1; e += 2) {
      int s0 = csr_src[e], s1 = csr_src[e + 1];
      unsigned int v0 = ((const unsigned int*)(hs + (size_t)s0 * 128))[lane];
      unsigned int v1 = ((const unsigned int*)(hs + (size_t)s1 * 128))[lane];
      ax += bf_lo(v0) + bf_lo(v1);
      ay += bf_hi(v0) + bf_hi(v1);
    }
    if (e < e1) {
      int s0 = csr_src[e];
      unsigned int v0 = ((const unsigned int*)(hs + (size_t)s0 * 128))[lane];
      ax += bf_lo(v0);
      ay += bf_hi(v0);
    }
    float di = dis[i];
    float2 o;
    o.x = fmaf(di, ax, bb.x);
    o.y = fmaf(di, ay, bb.y);
    ((float2*)(out + (size_t)i * 128))[lane] = o;
  }
}

// ---- fallback (plan A, round-1 verified): f32 aggregate then in-place GEMM ----
__global__ __launch_bounds__(256) void k_agg_f32(const float* __restrict__ X,
     const int* __restrict__ csr_src, const int* __restrict__ csr_off,
     const float* __restrict__ dis, float* __restrict__ out, int N) {
  int lane = threadIdx.x & 63;
  int gwave = (blockIdx.x * blockDim.x + threadIdx.x) >> 6;
  int nwave = (gridDim.x * blockDim.x) >> 6;
  for (int i = gwave; i < N; i += nwave) {
    float di = dis[i];
    float2 a = ((const float2*)(X + (size_t)i * 128))[lane];
    a.x *= di; a.y *= di;
    int e0 = csr_off[i], e1 = csr_off[i + 1];
    for (int e = e0; e < e1; ++e) {
      int sidx = csr_src[e];
      float dsv = dis[sidx];
      float2 v = ((const float2*)(X + (size_t)sidx * 128))[lane];
      a.x = fmaf(dsv, v.x, a.x);
      a.y = fmaf(dsv, v.y, a.y);
    }
    a.x *= di; a.y *= di;
    ((float2*)(out + (size_t)i * 128))[lane] = a;
  }
}

__global__ __launch_bounds__(256) void k_gemm_inplace(const float* __restrict__ W,
     const float* __restrict__ bias, float* __restrict__ out, int N) {
  __shared__ unsigned short Wt[128 * 136];
  __shared__ unsigned short A[64 * 136];
  int t = threadIdx.x;
  for (int idx = t; idx < 128 * 128; idx += 256) {
    int k = idx >> 7, j = idx & 127;
    Wt[j * 136 + k] = f2bf(W[idx]);
  }
  int r0 = blockIdx.x * 64;
  const float4* srcp = (const float4*)(out + (size_t)r0 * 128);
  for (int q = t; q < 64 * 32; q += 256) {
    int row = q >> 5, c4 = q & 31;
    float4 v;
    if (r0 + row < N) v = srcp[row * 32 + c4];
    else { v.x = v.y = v.z = v.w = 0.f; }
    int base = row * 136 + c4 * 4;
    A[base + 0] = f2bf(v.x); A[base + 1] = f2bf(v.y);
    A[base + 2] = f2bf(v.z); A[base + 3] = f2bf(v.w);
  }
  __syncthreads();
  int wv = t >> 6, lane = t & 63;
  int lr = lane & 15, lg = lane >> 4;
  int arow = wv * 16 + lr;
  short8v afr[4];
  #pragma unroll
  for (int kt = 0; kt < 4; ++kt) {
    const unsigned short* ap = &A[arow * 136 + kt * 32 + 4 * lg];
    short4v lo = *(const short4v*)ap;
    short4v hi = *(const short4v*)(ap + 16);
    afr[kt] = __builtin_shufflevector(lo, hi, 0, 1, 2, 3, 4, 5, 6, 7);
  }
  #pragma unroll
  for (int ct = 0; ct < 8; ++ct) {
    f32x4 acc = {0.f, 0.f, 0.f, 0.f};
    #pragma unroll
    for (int kt = 0; kt < 4; ++kt) {
      const unsigned short* bp = &Wt[(ct * 16 + lr) * 136 + kt * 32 + 4 * lg];
      short4v lo = *(const short4v*)bp;
      short4v hi = *(const short4v*)(bp + 16);
      short8v bfr = __builtin_shufflevector(lo, hi, 0, 1, 2, 3, 4, 5, 6, 7);
      acc = __builtin_amdgcn_mfma_f32_16x16x32_bf16(afr[kt], bfr, acc, 0, 0, 0);
    }
    int col = ct * 16 + lr;
    float bb = bias[col];
    #pragma unroll
    for (int r = 0; r < 4; ++r) {
      int row = r0 + wv * 16 + lg * 4 + r;
      if (row < N) out[(size_t)row * 128 + col] = acc[r] + bb;
    }
  }
}

extern "C" void kernel_launch(void* const* d_in, const int* in_sizes, int n_in,
                              void* d_out, int out_size, void* d_ws, size_t ws_size,
                              hipStream_t stream) {
  const float* X    = (const float*)d_in[0];
  const int*   edge = (const int*)d_in[1];
  const float* W    = (const float*)d_in[2];
  const float* bias = (const float*)d_in[3];
  float* out = (float*)d_out;
  int N = in_sizes[0] / 128;
  int E = in_sizes[1] / 2;
  const int* srcArr = edge;
  const int* dstArr = edge + E;

  char* w = (char*)d_ws;
  auto align = [](size_t x) { return (x + 255) & ~(size_t)255; };
  size_t o = 0;
  int*   deg      = (int*)(w + o);   o += align((size_t)N * 4);
  float* dis      = (float*)(w + o); o += align((size_t)N * 4);
  int*   cursor   = (int*)(w + o);   o += align((size_t)N * 4);
  int*   csr_off  = (int*)(w + o);   o += align(((size_t)N + 1) * 4);
  int*   csr_src  = (int*)(w + o);   o += align((size_t)E * 4);
  int*   partials = (int*)(w + o);   o += align((size_t)4096);
  unsigned short* hs = (unsigned short*)(w + o);
  size_t need = o + (size_t)N * 128 * 2;

  int nbN = (N + 255) / 256;
  int nbE = (E + 255) / 256;

  // CSR build (shared by both plans)
  k_init<<<nbN, 256, 0, stream>>>(deg, cursor, N);
  k_count<<<nbE, 256, 0, stream>>>(dstArr, deg, E);
  k_blocksum<<<nbN, 256, 0, stream>>>(deg, partials, dis, N);
  k_scan_partials<<<1, 1024, 0, stream>>>(partials, nbN);
  k_scan_final<<<nbN, 256, 0, stream>>>(deg, partials, csr_off, N, E);
  k_fill<<<nbE, 256, 0, stream>>>(srcArr, dstArr, csr_off, cursor, csr_src, E);

  if (ws_size >= need) {
    // plan B: GEMM -> bf16 hs, then L3-resident pull aggregation
    k_gemm_hs<<<(N + 63) / 64, 256, 0, stream>>>(X, W, dis, hs, N);
    k_agg_bf<<<2048, 256, 0, stream>>>(hs, csr_src, csr_off, dis, bias, out, N);
  } else {
    // plan A fallback (round-1 verified)
    k_agg_f32<<<2048, 256, 0, stream>>>(X, csr_src, csr_off, dis, out, N);
    k_gemm_inplace<<<(N + 63) / 64, 256, 0, stream>>>(W, bias, out, N);
  }
}

// Round 3
// 179.395 us; speedup vs baseline: 1.2599x; 1.1143x over previous
//
#include <hip/hip_runtime.h>
#include <hip/hip_bf16.h>
#include <stdint.h>

typedef __attribute__((ext_vector_type(8))) short short8v;
typedef __attribute__((ext_vector_type(4))) float f32x4;

__device__ __forceinline__ unsigned short f2bf(float f) {
  unsigned int u = __float_as_uint(f);
  u += 0x7fffu + ((u >> 16) & 1u);
  return (unsigned short)(u >> 16);
}
__device__ __forceinline__ float bf_lo(unsigned int v) { return __uint_as_float(v << 16); }
__device__ __forceinline__ float bf_hi(unsigned int v) { return __uint_as_float(v & 0xffff0000u); }

// ---- CSR build ----
__global__ void k_count(const int* __restrict__ dst, int* deg, int E) {
  int e = blockIdx.x * blockDim.x + threadIdx.x;
  if (e < E) atomicAdd(&deg[dst[e]], 1);
}

__global__ void k_blocksum(const int* __restrict__ deg, int* partials, float* dis, int N) {
  __shared__ int s[256];
  int t = threadIdx.x;
  int i = blockIdx.x * 256 + t;
  int c = (i < N) ? deg[i] : 0;
  if (i < N) dis[i] = rsqrtf((float)(c + 1));
  s[t] = c;
  __syncthreads();
  for (int off = 128; off > 0; off >>= 1) {
    if (t < off) s[t] += s[t + off];
    __syncthreads();
  }
  if (t == 0) partials[blockIdx.x] = s[0];
}

__global__ void k_scan_partials(int* partials, int nb) {
  __shared__ int s[1024];
  int t = threadIdx.x;
  s[t] = (t < nb) ? partials[t] : 0;
  __syncthreads();
  for (int off = 1; off < 1024; off <<= 1) {
    int v = (t >= off) ? s[t - off] : 0;
    __syncthreads();
    s[t] += v;
    __syncthreads();
  }
  if (t < nb) partials[t] = (t == 0) ? 0 : s[t - 1];  // exclusive
}

__global__ void k_scan_final(const int* __restrict__ deg, const int* __restrict__ partials,
                             int* csr_off, int N, int E) {
  __shared__ int s[256];
  int t = threadIdx.x;
  int i = blockIdx.x * 256 + t;
  int c = (i < N) ? deg[i] : 0;
  s[t] = c;
  __syncthreads();
  for (int off = 1; off < 256; off <<= 1) {
    int v = (t >= off) ? s[t - off] : 0;
    __syncthreads();
    s[t] += v;
    __syncthreads();
  }
  if (i < N) csr_off[i] = partials[blockIdx.x] + s[t] - c;  // exclusive
  if (i == 0) csr_off[N] = E;
}

__global__ void k_fill(const int* __restrict__ src, const int* __restrict__ dst,
                       const int* __restrict__ csr_off, int* cursor, int* csr_src, int E) {
  int e = blockIdx.x * blockDim.x + threadIdx.x;
  if (e < E) {
    int d = dst[e];
    int p = atomicAdd(&cursor[d], 1);
    csr_src[csr_off[d] + p] = src[e];
  }
}

// ---- W -> fragment-ordered bf16 (one time) ----
// Fragment f = ((ct*4+kt)*64 + lane)*8 + j holds bf16(W[k][col]) with
// col = ct*16 + (lane&15), k = kt*32 + 4*(lane>>4) + (j&3) + 16*(j>>2).
__global__ void k_wprep(const float* __restrict__ W, unsigned short* __restrict__ Wfrag) {
  int t = blockIdx.x * 256 + threadIdx.x;  // 0..16383
  int j = t & 7;
  int lane = (t >> 3) & 63;
  int ktct = t >> 9;
  int kt = ktct & 3, ct = ktct >> 2;
  int col = ct * 16 + (lane & 15);
  int k = kt * 32 + 4 * (lane >> 4) + (j & 3) + 16 * (j >> 2);
  Wfrag[t] = f2bf(W[k * 128 + col]);
}

__device__ __forceinline__ short8v pack8(float4 a, float4 b) {
  short8v r;
  r[0] = (short)f2bf(a.x); r[1] = (short)f2bf(a.y);
  r[2] = (short)f2bf(a.z); r[3] = (short)f2bf(a.w);
  r[4] = (short)f2bf(b.x); r[5] = (short)f2bf(b.y);
  r[6] = (short)f2bf(b.z); r[7] = (short)f2bf(b.w);
  return r;
}

// ---- GEMM: hs[row,:] = bf16(dis[row] * (X[row,:] @ W)) ----
__global__ __launch_bounds__(256) void k_gemm2(const float* __restrict__ X,
     const unsigned short* __restrict__ Wfrag, const float* __restrict__ dis,
     unsigned short* __restrict__ hs, int N, int NCH, int nb) {
  __shared__ unsigned short Wl[16384];   // 32 KB, fragment-ordered
  int t = threadIdx.x;
  for (int q = t; q < 2048; q += 256)
    ((uint4*)Wl)[q] = ((const uint4*)Wfrag)[q];
  __syncthreads();

  int wv = t >> 6, lane = t & 63;
  int lr = lane & 15, lg = lane >> 4;
  int c0 = (int)(((long long)blockIdx.x * NCH) / nb);
  int c1 = (int)(((long long)(blockIdx.x + 1) * NCH) / nb);

  for (int chunk = c0; chunk < c1; ++chunk) {
    int r0 = chunk * 64;
    int arow = r0 + wv * 16 + lr;
    short8v afr[4];
    if (r0 + 64 <= N) {
      const float* xp = X + (size_t)arow * 128 + 4 * lg;
      #pragma unroll
      for (int kt = 0; kt < 4; ++kt) {
        float4 v0 = *(const float4*)(xp + kt * 32);
        float4 v1 = *(const float4*)(xp + kt * 32 + 16);
        afr[kt] = pack8(v0, v1);
      }
    } else {
      #pragma unroll
      for (int kt = 0; kt < 4; ++kt) {
        float4 v0 = {0.f, 0.f, 0.f, 0.f}, v1 = {0.f, 0.f, 0.f, 0.f};
        if (arow < N) {
          const float* xp = X + (size_t)arow * 128 + 4 * lg;
          v0 = *(const float4*)(xp + kt * 32);
          v1 = *(const float4*)(xp + kt * 32 + 16);
        }
        afr[kt] = pack8(v0, v1);
      }
    }
    float dmul[4];
    #pragma unroll
    for (int r = 0; r < 4; ++r) {
      int row = r0 + wv * 16 + lg * 4 + r;
      dmul[r] = (row < N) ? dis[row] : 0.f;
    }
    #pragma unroll
    for (int ct = 0; ct < 8; ++ct) {
      f32x4 acc = {0.f, 0.f, 0.f, 0.f};
      #pragma unroll
      for (int kt = 0; kt < 4; ++kt) {
        short8v bfr = *(const short8v*)(Wl + (((ct * 4 + kt) * 64 + lane) * 8));
        acc = __builtin_amdgcn_mfma_f32_16x16x32_bf16(afr[kt], bfr, acc, 0, 0, 0);
      }
      int col = ct * 16 + lr;
      #pragma unroll
      for (int r = 0; r < 4; ++r) {
        int row = r0 + wv * 16 + lg * 4 + r;
        if (row < N) hs[(size_t)row * 128 + col] = f2bf(acc[r] * dmul[r]);
      }
    }
  }
}

// ---- aggregation: out[i] = dis[i]*(hs[i] + sum_{s in N(i)} hs[s]) + b ----
// 16 lanes per node; lane owns 16B (8 channels) of the 256B bf16 row.
__device__ __forceinline__ void acc8(float* a, uint4 g) {
  a[0] += bf_lo(g.x); a[1] += bf_hi(g.x);
  a[2] += bf_lo(g.y); a[3] += bf_hi(g.y);
  a[4] += bf_lo(g.z); a[5] += bf_hi(g.z);
  a[6] += bf_lo(g.w); a[7] += bf_hi(g.w);
}

__global__ __launch_bounds__(256) void k_agg2(const unsigned short* __restrict__ hs_,
     const int* __restrict__ csr_src, const int* __restrict__ csr_off,
     const float* __restrict__ dis, const float* __restrict__ bias,
     float* __restrict__ out, int N) {
  const uint4* hs = (const uint4*)hs_;
  int lane = threadIdx.x & 63;
  int c = lane & 15;
  int base = lane & 48;  // group base within wave
  int gid = (blockIdx.x * blockDim.x + threadIdx.x) >> 4;
  int G = (gridDim.x * blockDim.x) >> 4;
  int i0 = (int)(((long long)gid * N) / G);
  int i1 = (int)(((long long)(gid + 1) * N) / G);
  if (i0 >= i1) return;
  float4 bA = ((const float4*)bias)[c * 2];
  float4 bB = ((const float4*)bias)[c * 2 + 1];
  int e1prev = csr_off[i0];
  for (int i = i0; i < i1; ++i) {
    int e0 = e1prev;
    int e1 = csr_off[i + 1];
    e1prev = e1;
    float a[8];
    uint4 sv = hs[(size_t)i * 16 + c];
    a[0] = bf_lo(sv.x); a[1] = bf_hi(sv.x);
    a[2] = bf_lo(sv.y); a[3] = bf_hi(sv.y);
    a[4] = bf_lo(sv.z); a[5] = bf_hi(sv.z);
    a[6] = bf_lo(sv.w); a[7] = bf_hi(sv.w);
    int e = e0;
    while (e < e1) {
      int p = e + c;
      int myidx = (p < e1) ? csr_src[p] : 0;
      int kb = (e1 - e < 16) ? (e1 - e) : 16;
      for (int k = 0; k < kb; k += 4) {
        int s0 = __shfl(myidx, base + k);
        int s1 = __shfl(myidx, base + k + 1);
        int s2 = __shfl(myidx, base + k + 2);
        int s3 = __shfl(myidx, base + k + 3);
        bool v1 = (k + 1 < kb), v2 = (k + 2 < kb), v3 = (k + 3 < kb);
        uint4 g0 = hs[(size_t)s0 * 16 + c];
        uint4 g1 = hs[(size_t)(v1 ? s1 : i) * 16 + c];
        uint4 g2 = hs[(size_t)(v2 ? s2 : i) * 16 + c];
        uint4 g3 = hs[(size_t)(v3 ? s3 : i) * 16 + c];
        if (!v1) { g1.x = g1.y = g1.z = g1.w = 0u; }
        if (!v2) { g2.x = g2.y = g2.z = g2.w = 0u; }
        if (!v3) { g3.x = g3.y = g3.z = g3.w = 0u; }
        acc8(a, g0); acc8(a, g1); acc8(a, g2); acc8(a, g3);
      }
      e += kb;
    }
    float di = dis[i];
    float4 o0, o1;
    o0.x = fmaf(di, a[0], bA.x); o0.y = fmaf(di, a[1], bA.y);
    o0.z = fmaf(di, a[2], bA.z); o0.w = fmaf(di, a[3], bA.w);
    o1.x = fmaf(di, a[4], bB.x); o1.y = fmaf(di, a[5], bB.y);
    o1.z = fmaf(di, a[6], bB.z); o1.w = fmaf(di, a[7], bB.w);
    float4* op = (float4*)(out + (size_t)i * 128);
    op[c * 2] = o0;
    op[c * 2 + 1] = o1;
  }
}

extern "C" void kernel_launch(void* const* d_in, const int* in_sizes, int n_in,
                              void* d_out, int out_size, void* d_ws, size_t ws_size,
                              hipStream_t stream) {
  const float* X    = (const float*)d_in[0];
  const int*   edge = (const int*)d_in[1];
  const float* W    = (const float*)d_in[2];
  const float* bias = (const float*)d_in[3];
  float* out = (float*)d_out;
  int N = in_sizes[0] / 128;
  int E = in_sizes[1] / 2;
  const int* srcArr = edge;
  const int* dstArr = edge + E;

  char* w = (char*)d_ws;
  auto align = [](size_t x) { return (x + 255) & ~(size_t)255; };
  size_t o = 0;
  int*   deg      = (int*)(w + o);   o += align((size_t)N * 4);
  int*   cursor   = (int*)(w + o);   o += align((size_t)N * 4);
  float* dis      = (float*)(w + o); o += align((size_t)N * 4);
  int*   csr_off  = (int*)(w + o);   o += align(((size_t)N + 1) * 4);
  int*   csr_src  = (int*)(w + o);   o += align((size_t)E * 4);
  int*   partials = (int*)(w + o);   o += align((size_t)4096 * 4);
  unsigned short* Wfrag = (unsigned short*)(w + o); o += align((size_t)16384 * 2);
  unsigned short* hs    = (unsigned short*)(w + o);

  int nbN = (N + 255) / 256;
  int nbE = (E + 255) / 256;
  int NCH = (N + 63) / 64;
  int nbG = 1024;

  // deg and cursor are adjacent: one async memset zeroes both
  hipMemsetAsync(deg, 0, align((size_t)N * 4) + (size_t)N * 4, stream);
  k_wprep<<<64, 256, 0, stream>>>(W, Wfrag);
  k_count<<<nbE, 256, 0, stream>>>(dstArr, deg, E);
  k_blocksum<<<nbN, 256, 0, stream>>>(deg, partials, dis, N);
  k_scan_partials<<<1, 1024, 0, stream>>>(partials, nbN);
  k_scan_final<<<nbN, 256, 0, stream>>>(deg, partials, csr_off, N, E);
  k_fill<<<nbE, 256, 0, stream>>>(srcArr, dstArr, csr_off, cursor, csr_src, E);
  k_gemm2<<<nbG, 256, 0, stream>>>(X, Wfrag, dis, hs, N, NCH, nbG);
  k_agg2<<<2048, 256, 0, stream>>>(hs, csr_src, csr_off, dis, bias, out, N);
}

// Round 4
// 162.981 us; speedup vs baseline: 1.3868x; 1.1007x over previous
//
#include <hip/hip_runtime.h>
#include <hip/hip_bf16.h>
#include <stdint.h>

typedef __attribute__((ext_vector_type(8))) short short8v;
typedef __attribute__((ext_vector_type(4))) float f32x4;

__device__ __forceinline__ unsigned short f2bf(float f) {
  unsigned int u = __float_as_uint(f);
  u += 0x7fffu + ((u >> 16) & 1u);
  return (unsigned short)(u >> 16);
}
__device__ __forceinline__ unsigned int pack2bf(float a, float b) {
  return (unsigned int)f2bf(a) | ((unsigned int)f2bf(b) << 16);
}
__device__ __forceinline__ float bf_lo(unsigned int v) { return __uint_as_float(v << 16); }
__device__ __forceinline__ float bf_hi(unsigned int v) { return __uint_as_float(v & 0xffff0000u); }

// ---- CSR build ----
__global__ void k_count(const int* __restrict__ dst, int* deg, int E) {
  int e = blockIdx.x * blockDim.x + threadIdx.x;
  if (e < E) atomicAdd(&deg[dst[e]], 1);
}

__global__ void k_blocksum(const int* __restrict__ deg, int* partials, float* dis, int N) {
  __shared__ int s[256];
  int t = threadIdx.x;
  int i = blockIdx.x * 256 + t;
  int c = (i < N) ? deg[i] : 0;
  if (i < N) dis[i] = rsqrtf((float)(c + 1));
  s[t] = c;
  __syncthreads();
  for (int off = 128; off > 0; off >>= 1) {
    if (t < off) s[t] += s[t + off];
    __syncthreads();
  }
  if (t == 0) partials[blockIdx.x] = s[0];
}

__global__ void k_scan_partials(int* partials, int nb) {
  __shared__ int s[1024];
  int t = threadIdx.x;
  s[t] = (t < nb) ? partials[t] : 0;
  __syncthreads();
  for (int off = 1; off < 1024; off <<= 1) {
    int v = (t >= off) ? s[t - off] : 0;
    __syncthreads();
    s[t] += v;
    __syncthreads();
  }
  if (t < nb) partials[t] = (t == 0) ? 0 : s[t - 1];  // exclusive
}

__global__ void k_scan_final(const int* __restrict__ deg, const int* __restrict__ partials,
                             int* csr_off, int N, int E) {
  __shared__ int s[256];
  int t = threadIdx.x;
  int i = blockIdx.x * 256 + t;
  int c = (i < N) ? deg[i] : 0;
  s[t] = c;
  __syncthreads();
  for (int off = 1; off < 256; off <<= 1) {
    int v = (t >= off) ? s[t - off] : 0;
    __syncthreads();
    s[t] += v;
    __syncthreads();
  }
  if (i < N) csr_off[i] = partials[blockIdx.x] + s[t] - c;  // exclusive
  if (i == 0) csr_off[N] = E;
}

__global__ void k_fill(const int* __restrict__ src, const int* __restrict__ dst,
                       const int* __restrict__ csr_off, int* cursor, int* csr_src, int E) {
  int e = blockIdx.x * blockDim.x + threadIdx.x;
  if (e < E) {
    int d = dst[e];
    int p = atomicAdd(&cursor[d], 1);
    csr_src[csr_off[d] + p] = src[e];
  }
}

// ---- W -> fragment-ordered bf16 (one time) ----
// Wfrag[((ct*4+kt)*64 + lane)*8 + j] = bf16(W[k][col]),
// col = ct*16 + (lane&15), k = kt*32 + 4*(lane>>4) + (j&3) + 16*(j>>2).
__global__ void k_wprep(const float* __restrict__ W, unsigned short* __restrict__ Wfrag) {
  int t = blockIdx.x * 256 + threadIdx.x;  // 0..16383
  int j = t & 7;
  int lane = (t >> 3) & 63;
  int ktct = t >> 9;
  int kt = ktct & 3, ct = ktct >> 2;
  int col = ct * 16 + (lane & 15);
  int k = kt * 32 + 4 * (lane >> 4) + (j & 3) + 16 * (j >> 2);
  Wfrag[t] = f2bf(W[k * 128 + col]);
}

__device__ __forceinline__ short8v pack8(float4 a, float4 b) {
  short8v r;
  r[0] = (short)f2bf(a.x); r[1] = (short)f2bf(a.y);
  r[2] = (short)f2bf(a.z); r[3] = (short)f2bf(a.w);
  r[4] = (short)f2bf(b.x); r[5] = (short)f2bf(b.y);
  r[6] = (short)f2bf(b.z); r[7] = (short)f2bf(b.w);
  return r;
}

// ---- GEMM (swapped operands): lane holds 4 consecutive hs cols of one row ----
// hs[row,:] = bf16(dis[row] * (X[row,:] @ W)), one 64-row chunk per block.
__global__ __launch_bounds__(256) void k_gemm3(const float* __restrict__ X,
     const unsigned short* __restrict__ Wfrag, const float* __restrict__ dis,
     unsigned short* __restrict__ hs, int N) {
  __shared__ unsigned short Wl[16384];   // 32 KB, fragment-ordered
  int t = threadIdx.x;
  #pragma unroll
  for (int q = 0; q < 8; ++q)
    ((uint4*)Wl)[q * 256 + t] = ((const uint4*)Wfrag)[q * 256 + t];
  __syncthreads();

  int wv = t >> 6, lane = t & 63;
  int lr = lane & 15, lg = lane >> 4;
  int row = blockIdx.x * 64 + wv * 16 + lr;

  short8v afr[4];   // B-operand: lane holds X[row][k(j)]
  if (row < N) {
    const float* xp = X + (size_t)row * 128 + 4 * lg;
    #pragma unroll
    for (int kt = 0; kt < 4; ++kt) {
      float4 v0 = *(const float4*)(xp + kt * 32);
      float4 v1 = *(const float4*)(xp + kt * 32 + 16);
      afr[kt] = pack8(v0, v1);
    }
  } else {
    #pragma unroll
    for (int kt = 0; kt < 4; ++kt) {
      float4 z = {0.f, 0.f, 0.f, 0.f};
      afr[kt] = pack8(z, z);
    }
  }
  float d = (row < N) ? dis[row] : 0.f;

  #pragma unroll
  for (int ct = 0; ct < 8; ++ct) {
    f32x4 acc = {0.f, 0.f, 0.f, 0.f};
    #pragma unroll
    for (int kt = 0; kt < 4; ++kt) {
      short8v wfr = *(const short8v*)(Wl + (((ct * 4 + kt) * 64 + lane) * 8));
      acc = __builtin_amdgcn_mfma_f32_16x16x32_bf16(wfr, afr[kt], acc, 0, 0, 0);
    }
    if (row < N) {
      uint2 uu;
      uu.x = pack2bf(acc[0] * d, acc[1] * d);
      uu.y = pack2bf(acc[2] * d, acc[3] * d);
      *(uint2*)(hs + (size_t)row * 128 + ct * 16 + 4 * lg) = uu;
    }
  }
}

// ---- aggregation: out[i] = dis[i]*(hs[i] + sum_{s in N(i)} hs[s]) + b ----
// 16 lanes per node; lane owns 16B (8 channels) of the 256B bf16 row.
__device__ __forceinline__ void acc8(float* a, uint4 g) {
  a[0] += bf_lo(g.x); a[1] += bf_hi(g.x);
  a[2] += bf_lo(g.y); a[3] += bf_hi(g.y);
  a[4] += bf_lo(g.z); a[5] += bf_hi(g.z);
  a[6] += bf_lo(g.w); a[7] += bf_hi(g.w);
}

__global__ __launch_bounds__(256) void k_agg2(const unsigned short* __restrict__ hs_,
     const int* __restrict__ csr_src, const int* __restrict__ csr_off,
     const float* __restrict__ dis, const float* __restrict__ bias,
     float* __restrict__ out, int N) {
  const uint4* hs = (const uint4*)hs_;
  int lane = threadIdx.x & 63;
  int c = lane & 15;
  int base = lane & 48;  // group base within wave
  int gid = (blockIdx.x * blockDim.x + threadIdx.x) >> 4;
  int G = (gridDim.x * blockDim.x) >> 4;
  int i0 = (int)(((long long)gid * N) / G);
  int i1 = (int)(((long long)(gid + 1) * N) / G);
  if (i0 >= i1) return;
  float4 bA = ((const float4*)bias)[c * 2];
  float4 bB = ((const float4*)bias)[c * 2 + 1];
  int e1prev = csr_off[i0];
  for (int i = i0; i < i1; ++i) {
    int e0 = e1prev;
    int e1 = csr_off[i + 1];
    e1prev = e1;
    float a[8];
    uint4 sv = hs[(size_t)i * 16 + c];
    a[0] = bf_lo(sv.x); a[1] = bf_hi(sv.x);
    a[2] = bf_lo(sv.y); a[3] = bf_hi(sv.y);
    a[4] = bf_lo(sv.z); a[5] = bf_hi(sv.z);
    a[6] = bf_lo(sv.w); a[7] = bf_hi(sv.w);
    int e = e0;
    while (e < e1) {
      int p = e + c;
      int myidx = (p < e1) ? csr_src[p] : 0;
      int kb = (e1 - e < 16) ? (e1 - e) : 16;
      int k = 0;
      // unguarded 8-wide full passes (deep MLP, zero dummy loads)
      for (; k + 8 <= kb; k += 8) {
        int s[8];
        #pragma unroll
        for (int q = 0; q < 8; ++q) s[q] = __shfl(myidx, base + k + q);
        uint4 g[8];
        #pragma unroll
        for (int q = 0; q < 8; ++q) g[q] = hs[(size_t)s[q] * 16 + c];
        #pragma unroll
        for (int q = 0; q < 8; ++q) acc8(a, g[q]);
      }
      // guarded 4-wide tail
      for (; k < kb; k += 4) {
        int s0 = __shfl(myidx, base + k);
        int s1 = __shfl(myidx, base + k + 1);
        int s2 = __shfl(myidx, base + k + 2);
        int s3 = __shfl(myidx, base + k + 3);
        bool v1 = (k + 1 < kb), v2 = (k + 2 < kb), v3 = (k + 3 < kb);
        uint4 g0 = hs[(size_t)s0 * 16 + c];
        uint4 g1 = hs[(size_t)(v1 ? s1 : i) * 16 + c];
        uint4 g2 = hs[(size_t)(v2 ? s2 : i) * 16 + c];
        uint4 g3 = hs[(size_t)(v3 ? s3 : i) * 16 + c];
        if (!v1) { g1.x = g1.y = g1.z = g1.w = 0u; }
        if (!v2) { g2.x = g2.y = g2.z = g2.w = 0u; }
        if (!v3) { g3.x = g3.y = g3.z = g3.w = 0u; }
        acc8(a, g0); acc8(a, g1); acc8(a, g2); acc8(a, g3);
      }
      e += kb;
    }
    float di = dis[i];
    float4 o0, o1;
    o0.x = fmaf(di, a[0], bA.x); o0.y = fmaf(di, a[1], bA.y);
    o0.z = fmaf(di, a[2], bA.z); o0.w = fmaf(di, a[3], bA.w);
    o1.x = fmaf(di, a[4], bB.x); o1.y = fmaf(di, a[5], bB.y);
    o1.z = fmaf(di, a[6], bB.z); o1.w = fmaf(di, a[7], bB.w);
    float4* op = (float4*)(out + (size_t)i * 128);
    op[c * 2] = o0;
    op[c * 2 + 1] = o1;
  }
}

extern "C" void kernel_launch(void* const* d_in, const int* in_sizes, int n_in,
                              void* d_out, int out_size, void* d_ws, size_t ws_size,
                              hipStream_t stream) {
  const float* X    = (const float*)d_in[0];
  const int*   edge = (const int*)d_in[1];
  const float* W    = (const float*)d_in[2];
  const float* bias = (const float*)d_in[3];
  float* out = (float*)d_out;
  int N = in_sizes[0] / 128;
  int E = in_sizes[1] / 2;
  const int* srcArr = edge;
  const int* dstArr = edge + E;

  char* w = (char*)d_ws;
  auto align = [](size_t x) { return (x + 255) & ~(size_t)255; };
  size_t o = 0;
  int*   deg      = (int*)(w + o);   o += align((size_t)N * 4);
  int*   cursor   = (int*)(w + o);   o += align((size_t)N * 4);
  float* dis      = (float*)(w + o); o += align((size_t)N * 4);
  int*   csr_off  = (int*)(w + o);   o += align(((size_t)N + 1) * 4);
  int*   csr_src  = (int*)(w + o);   o += align((size_t)E * 4);
  int*   partials = (int*)(w + o);   o += align((size_t)4096 * 4);
  unsigned short* Wfrag = (unsigned short*)(w + o); o += align((size_t)16384 * 2);
  unsigned short* hs    = (unsigned short*)(w + o);

  int nbN = (N + 255) / 256;
  int nbE = (E + 255) / 256;

  // deg and cursor are adjacent: one async memset zeroes both
  hipMemsetAsync(deg, 0, align((size_t)N * 4) + (size_t)N * 4, stream);
  k_wprep<<<64, 256, 0, stream>>>(W, Wfrag);
  k_count<<<nbE, 256, 0, stream>>>(dstArr, deg, E);
  k_blocksum<<<nbN, 256, 0, stream>>>(deg, partials, dis, N);
  k_scan_partials<<<1, 1024, 0, stream>>>(partials, nbN);
  k_scan_final<<<nbN, 256, 0, stream>>>(deg, partials, csr_off, N, E);
  k_fill<<<nbE, 256, 0, stream>>>(srcArr, dstArr, csr_off, cursor, csr_src, E);
  k_gemm3<<<(N + 63) / 64, 256, 0, stream>>>(X, Wfrag, dis, hs, N);
  k_agg2<<<2048, 256, 0, stream>>>(hs, csr_src, csr_off, dis, bias, out, N);
}